// Round 2
// baseline (3360.779 us; speedup 1.0000x reference)
//
#include <hip/hip_runtime.h>
#include <hip/hip_bf16.h>
#include <cstdint>
#include <cstddef>

#define T_LEN 512
#define B_SZ  512
#define F_IN  64
#define H_DIM 128
#define NSTEP 8

typedef __attribute__((ext_vector_type(8))) short short8;
typedef __attribute__((ext_vector_type(4))) float f32x4;

__device__ __forceinline__ float fsig(float x) { return 1.0f / (1.0f + __expf(-x)); }
__device__ __forceinline__ float ftanh(float x) {
  float e = __expf(-2.0f * fabsf(x));
  float t = (1.0f - e) / (1.0f + e);
  return copysignf(t, x);
}
__device__ __forceinline__ unsigned short bf16hi(float x) {
  __hip_bfloat16 h = __float2bfloat16(x);
  return *(unsigned short*)&h;
}
__device__ __forceinline__ float bf2f(unsigned short u) {
  return __uint_as_float(((unsigned)u) << 16);
}
__device__ __forceinline__ float bflo(unsigned u) { return __uint_as_float(u << 16); }
__device__ __forceinline__ float bfhi(unsigned u) { return __uint_as_float(u & 0xffff0000u); }

// DPP cross-lane add within 16-lane rows (decoder scores)
template <int CTRL>
__device__ __forceinline__ float dpp_add(float v) {
  int p = __builtin_amdgcn_update_dpp(0, __float_as_int(v), CTRL, 0xF, 0xF, true);
  return v + __int_as_float(p);
}
__device__ __forceinline__ float row_sum16(float v) {
  v = dpp_add<0xB1>(v);
  v = dpp_add<0x4E>(v);
  v = dpp_add<0x124>(v);
  v = dpp_add<0x128>(v);
  return v;
}

// split 8 consecutive fp32 into bf16 hi/lo short8 fragments
__device__ __forceinline__ void split8(const float* p, short8& hi, short8& lo) {
  #pragma unroll
  for (int i = 0; i < 8; ++i) {
    const float v = p[i];
    const unsigned short h = bf16hi(v);
    hi[i] = (short)h;
    lo[i] = (short)bf16hi(v - bf2f(h));
  }
}

// split two adjacent float4 (8 fp32) into bf16 hi/lo short8 fragments
__device__ __forceinline__ void split_f4pair(const float4 a, const float4 b,
                                             short8& hi, short8& lo) {
  const float v[8] = {a.x, a.y, a.z, a.w, b.x, b.y, b.z, b.w};
  #pragma unroll
  for (int j = 0; j < 8; ++j) {
    const unsigned short h = bf16hi(v[j]);
    hi[j] = (short)h;
    lo[j] = (short)bf16hi(v[j] - bf2f(h));
  }
}

// -------------------------------------------------------------------------
// Split the 3 encoder w_ih matrices into bf16 hi/lo pairs (one-time prep).
// -------------------------------------------------------------------------
__global__ __launch_bounds__(256) void prep_split(
    const float* __restrict__ w0, const float* __restrict__ w1,
    const float* __restrict__ w2,
    unsigned short* __restrict__ hi, unsigned short* __restrict__ lo)
{
  const int i = blockIdx.x * 256 + threadIdx.x;
  if (i >= 122880) return;
  float v = (i < 24576) ? w0[i] : ((i < 73728) ? w1[i - 24576] : w2[i - 73728]);
  const unsigned short h = bf16hi(v);
  hi[i] = h;
  lo[i] = bf16hi(v - bf2f(h));
}

// -------------------------------------------------------------------------
// Fused GRU layer: gx (input GEMM) + recurrence in ONE kernel.
// 256 blocks x 2 batch rows, 512 thr / 8 waves, T=512 steps in-kernel.
//
// gh (recurrence) path is the proven rec_mfma structure: wave w owns
// channels c in [16w,16w+16) across 3 gates; after MFMA, quad-0 lane l16
// holds gh for channel c rows 0,1 in C regs 0,1; gates compute in-lane.
//
// gx path: does NOT depend on h, so it is blocked over 8 timesteps:
// the MFMA A-tile (16 rows) = 8 timesteps x 2 batch rows at FULL
// utilization, computed once per 8-step group at the group boundary.
// w_ih B-fragments stream from the prep-split bf16 buffers (L2-resident);
// input rows (x for layer0, prev-layer Hhi/Hlo for layers 1-2) are
// register-prefetched one full group ahead. Per step, the 6 gate inputs
// are pulled from the gx accumulator with __shfl (owner quad = tt>>1,
// reg = 2*(tt&1)+rr, all compile-time via the unrolled 8-step loop).
//
// In-place safety (layers 1-2 read and write Hhi/Hlo): each block touches
// only its own batch rows b0,b0+1; the prefetch of timesteps [tg+8,tg+16)
// is issued >= 8 barriers (each with vmcnt drain) before those addresses
// are overwritten at steps tg+8.. .
// -------------------------------------------------------------------------
template <int IS_L0>
__global__ __launch_bounds__(512, 1) void rec_fused(
    const float* x,                         // layer0 input (B,T,F), else unused
    const unsigned short* Xhi,              // layers>=1: prev-layer H hi (T,B,H)
    const unsigned short* Xlo,
    const unsigned short* __restrict__ Wih_hi,  // (384, KD) bf16 hi
    const unsigned short* __restrict__ Wih_lo,  // (384, KD) bf16 lo
    const float* __restrict__ w_hh, const float* __restrict__ b_ih,
    const float* __restrict__ b_hh,
    unsigned short* Hhi, unsigned short* Hlo)   // out (T,B,H)
{
  constexpr int KD  = IS_L0 ? 64 : 128;
  constexpr int NCK = KD / 32;

  __shared__ unsigned short hsh[2][256];   // [buf][row*128 + c]
  __shared__ unsigned short hsl[2][256];

  const int tid  = threadIdx.x;
  const int wave = tid >> 6, lane = tid & 63;
  const int quad = lane >> 4, l16 = lane & 15;
  const int b0   = blockIdx.x * 2;
  const int c    = wave * 16 + l16;        // owned channel (quad-0 lanes)

  // w_hh B-fragments: gate g, lane n = g*128 + c, k = ck*32 + quad*8
  short8 Bh[3][4], Bl[3][4];
  #pragma unroll
  for (int g = 0; g < 3; ++g) {
    #pragma unroll
    for (int ck = 0; ck < 4; ++ck)
      split8(&w_hh[(size_t)(g * 128 + c) * 128 + ck * 32 + quad * 8],
             Bh[g][ck], Bl[g][ck]);
  }

  float bias_r = 0.f, bias_z = 0.f, bihn = 0.f, bhhn = 0.f, h0 = 0.f, h1 = 0.f;
  if (quad == 0) {
    bias_r = b_ih[c] + b_hh[c];            // r-gate: b_ih + b_hh fold
    bias_z = b_ih[c + 128] + b_hh[c + 128];
    bihn = b_ih[c + 256];                  // n-gate biases stay separate
    bhhn = b_hh[c + 256];
    hsh[0][c] = 0; hsh[0][128 + c] = 0;    // h starts at 0 every layer
    hsl[0][c] = 0; hsl[0][128 + c] = 0;
  }

  // per-lane X source coords: A-row l16 <-> (t_off = l16>>1, batch = b0+(l16&1))
  const int xt = l16 >> 1;
  const int xb = b0 + (l16 & 1);

  uint4  xh[4], xl[4];   // layers >= 1: bf16 hi/lo of prev-layer H
  float4 xf[4];          // layer 0: fp32 x (2ck x 2 float4)

  // prefetch group 0
  if constexpr (IS_L0) {
    #pragma unroll
    for (int ck = 0; ck < 2; ++ck) {
      const size_t base = ((size_t)xb * T_LEN + xt) * 64 + ck * 32 + quad * 8;
      xf[ck * 2]     = *(const float4*)&x[base];
      xf[ck * 2 + 1] = *(const float4*)&x[base + 4];
    }
  } else {
    #pragma unroll
    for (int ck = 0; ck < 4; ++ck) {
      const size_t base = ((size_t)xt * B_SZ + xb) * 128 + ck * 32 + quad * 8;
      xh[ck] = *(const uint4*)&Xhi[base];
      xl[ck] = *(const uint4*)&Xlo[base];
    }
  }
  __syncthreads();

  for (int tg = 0; tg < T_LEN; tg += 8) {
    // ---- group boundary: gx block MFMA (A = 8 timesteps x 2 batch rows) ----
    short8 Xhf[NCK], Xlf[NCK];
    if constexpr (IS_L0) {
      #pragma unroll
      for (int ck = 0; ck < 2; ++ck)
        split_f4pair(xf[ck * 2], xf[ck * 2 + 1], Xhf[ck], Xlf[ck]);
    } else {
      #pragma unroll
      for (int ck = 0; ck < 4; ++ck) {
        Xhf[ck] = *(const short8*)&xh[ck];
        Xlf[ck] = *(const short8*)&xl[ck];
      }
    }
    f32x4 a2[3][2];
    #pragma unroll
    for (int g = 0; g < 3; ++g) {
      a2[g][0] = (f32x4){0.f, 0.f, 0.f, 0.f};
      a2[g][1] = (f32x4){0.f, 0.f, 0.f, 0.f};
    }
    #pragma unroll
    for (int ck = 0; ck < NCK; ++ck) {
      const int p = ck >> 1;
      #pragma unroll
      for (int g = 0; g < 3; ++g) {
        const size_t wb = (size_t)(g * 128 + c) * KD + ck * 32 + quad * 8;
        const short8 wh = *(const short8*)&Wih_hi[wb];
        const short8 wl = *(const short8*)&Wih_lo[wb];
        a2[g][p] = __builtin_amdgcn_mfma_f32_16x16x32_bf16(Xhf[ck], wh, a2[g][p], 0, 0, 0);
        a2[g][p] = __builtin_amdgcn_mfma_f32_16x16x32_bf16(Xhf[ck], wl, a2[g][p], 0, 0, 0);
        a2[g][p] = __builtin_amdgcn_mfma_f32_16x16x32_bf16(Xlf[ck], wh, a2[g][p], 0, 0, 0);
      }
    }
    f32x4 accx[3];
    #pragma unroll
    for (int g = 0; g < 3; ++g) accx[g] = a2[g][0] + a2[g][1];

    // keep next-group loads from being hoisted above the boundary MFMAs
    __builtin_amdgcn_sched_barrier(0);

    // prefetch next group's X rows (consumed 8 steps later -> full slack)
    if (tg + 8 < T_LEN) {
      if constexpr (IS_L0) {
        #pragma unroll
        for (int ck = 0; ck < 2; ++ck) {
          const size_t base = ((size_t)xb * T_LEN + tg + 8 + xt) * 64 + ck * 32 + quad * 8;
          xf[ck * 2]     = *(const float4*)&x[base];
          xf[ck * 2 + 1] = *(const float4*)&x[base + 4];
        }
      } else {
        #pragma unroll
        for (int ck = 0; ck < 4; ++ck) {
          const size_t base = ((size_t)(tg + 8 + xt) * B_SZ + xb) * 128 + ck * 32 + quad * 8;
          xh[ck] = *(const uint4*)&Xhi[base];
          xl[ck] = *(const uint4*)&Xlo[base];
        }
      }
    }

    // ---- 8 recurrence steps (unrolled: all accx indices compile-time) ----
    #pragma unroll
    for (int tt = 0; tt < 8; ++tt) {
      const int tl = tg + tt;

      // extract this step's gx values from the group accumulator:
      // value for (tt, rr) lives in quad tt>>1, C-reg 2*(tt&1)+rr, col l16
      const int srcl = ((tt >> 1) << 4) | l16;
      const float gxr0 = __shfl(accx[0][2 * (tt & 1)],     srcl);
      const float gxr1 = __shfl(accx[0][2 * (tt & 1) + 1], srcl);
      const float gxz0 = __shfl(accx[1][2 * (tt & 1)],     srcl);
      const float gxz1 = __shfl(accx[1][2 * (tt & 1) + 1], srcl);
      const float gxn0 = __shfl(accx[2][2 * (tt & 1)],     srcl);
      const float gxn1 = __shfl(accx[2][2 * (tt & 1) + 1], srcl);

      // h A-fragments: lane row = l16; rows >=2 are zeros (C rows unused)
      short8 Ahf[4], Alf[4];
      if (l16 < 2) {
        #pragma unroll
        for (int ck = 0; ck < 4; ++ck) {
          const int ad = l16 * 128 + ck * 32 + quad * 8;
          Ahf[ck] = *(const short8*)&hsh[tt & 1][ad];
          Alf[ck] = *(const short8*)&hsl[tt & 1][ad];
        }
      } else {
        #pragma unroll
        for (int ck = 0; ck < 4; ++ck) {
          Ahf[ck] = (short8){0, 0, 0, 0, 0, 0, 0, 0};
          Alf[ck] = (short8){0, 0, 0, 0, 0, 0, 0, 0};
        }
      }

      // 36 gh MFMA/wave; 2 partial accumulators per gate halve the dep chain
      f32x4 acc[3][2];
      #pragma unroll
      for (int g = 0; g < 3; ++g) {
        acc[g][0] = (f32x4){0.f, 0.f, 0.f, 0.f};
        acc[g][1] = (f32x4){0.f, 0.f, 0.f, 0.f};
      }
      #pragma unroll
      for (int ck = 0; ck < 4; ++ck) {
        const int p = ck >> 1;
        #pragma unroll
        for (int g = 0; g < 3; ++g) {
          acc[g][p] = __builtin_amdgcn_mfma_f32_16x16x32_bf16(Ahf[ck], Bh[g][ck], acc[g][p], 0, 0, 0);
          acc[g][p] = __builtin_amdgcn_mfma_f32_16x16x32_bf16(Ahf[ck], Bl[g][ck], acc[g][p], 0, 0, 0);
          acc[g][p] = __builtin_amdgcn_mfma_f32_16x16x32_bf16(Alf[ck], Bh[g][ck], acc[g][p], 0, 0, 0);
        }
      }

      // in-lane gates (quad-0): gh for channel c rows 0,1 are regs 0,1
      if (quad == 0) {
        const float ghr0 = acc[0][0][0] + acc[0][1][0];
        const float ghr1 = acc[0][0][1] + acc[0][1][1];
        const float ghz0 = acc[1][0][0] + acc[1][1][0];
        const float ghz1 = acc[1][0][1] + acc[1][1][1];
        const float ghn0 = acc[2][0][0] + acc[2][1][0];
        const float ghn1 = acc[2][0][1] + acc[2][1][1];
        const float r0 = fsig(gxr0 + ghr0 + bias_r);
        const float z0 = fsig(gxz0 + ghz0 + bias_z);
        const float nv0 = ftanh(gxn0 + bihn + r0 * (ghn0 + bhhn));
        const float hn0 = (1.0f - z0) * nv0 + z0 * h0;
        const float r1 = fsig(gxr1 + ghr1 + bias_r);
        const float z1 = fsig(gxz1 + ghz1 + bias_z);
        const float nv1 = ftanh(gxn1 + bihn + r1 * (ghn1 + bhhn));
        const float hn1 = (1.0f - z1) * nv1 + z1 * h1;
        h0 = hn0; h1 = hn1;
        const int nb = (tt + 1) & 1;
        const unsigned short hh0 = bf16hi(hn0), hh1 = bf16hi(hn1);
        const unsigned short hl0 = bf16hi(hn0 - bf2f(hh0));
        const unsigned short hl1 = bf16hi(hn1 - bf2f(hh1));
        hsh[nb][c] = hh0;       hsh[nb][128 + c] = hh1;
        hsl[nb][c] = hl0;       hsl[nb][128 + c] = hl1;
        const size_t ob = ((size_t)tl * B_SZ + b0) * 128 + c;
        Hhi[ob] = hh0;        Hlo[ob] = hl0;
        Hhi[ob + 128] = hh1;  Hlo[ob + 128] = hl1;
      }
      __syncthreads();
    }
  }
}

// -------------------------------------------------------------------------
// keys = H @ aWk^T + abk, split-bf16 MFMA, output Khi (bf16 RNE) only.
// -------------------------------------------------------------------------
__global__ __launch_bounds__(256) void keys_gemm(
    const unsigned short* __restrict__ Ahi, const unsigned short* __restrict__ Alo,
    const float* __restrict__ aWk, const float* __restrict__ abk,
    unsigned short* __restrict__ Khi)
{
  __shared__ unsigned short Ah[64 * 40], Al[64 * 40];
  __shared__ unsigned short Bh[128 * 136], Bl[128 * 136];
  const int tid  = threadIdx.x;
  const int wave = tid >> 6, lane = tid & 63;
  const int quad = lane >> 4, l16 = lane & 15;
  const size_t m0 = (size_t)blockIdx.x * 64;

  for (int i = tid; i < 16384; i += 256) {
    const float v = aWk[i];
    const unsigned short h = bf16hi(v);
    const int r = i >> 7, k = i & 127;
    Bh[r * 136 + k] = h;
    Bl[r * 136 + k] = bf16hi(v - bf2f(h));
  }

  f32x4 acc[8];
  #pragma unroll
  for (int i = 0; i < 8; ++i) acc[i] = (f32x4){0.f, 0.f, 0.f, 0.f};
  float bias[8];
  #pragma unroll
  for (int nt = 0; nt < 8; ++nt) bias[nt] = abk[nt * 16 + l16];

  const int r = tid >> 2, c8 = (tid & 3) * 8;
  for (int kc = 0; kc < 128; kc += 32) {
    __syncthreads();
    const size_t src = (m0 + r) * 128 + kc + c8;
    *(uint4*)&Ah[r * 40 + c8] = *(const uint4*)&Ahi[src];
    *(uint4*)&Al[r * 40 + c8] = *(const uint4*)&Alo[src];
    __syncthreads();
    const short8 a_hi = *(const short8*)&Ah[(wave * 16 + l16) * 40 + quad * 8];
    const short8 a_lo = *(const short8*)&Al[(wave * 16 + l16) * 40 + quad * 8];
    #pragma unroll
    for (int nt = 0; nt < 8; ++nt) {
      const short8 b_hi = *(const short8*)&Bh[(nt * 16 + l16) * 136 + kc + quad * 8];
      const short8 b_lo = *(const short8*)&Bl[(nt * 16 + l16) * 136 + kc + quad * 8];
      acc[nt] = __builtin_amdgcn_mfma_f32_16x16x32_bf16(a_hi, b_hi, acc[nt], 0, 0, 0);
      acc[nt] = __builtin_amdgcn_mfma_f32_16x16x32_bf16(a_hi, b_lo, acc[nt], 0, 0, 0);
      acc[nt] = __builtin_amdgcn_mfma_f32_16x16x32_bf16(a_lo, b_hi, acc[nt], 0, 0, 0);
    }
  }
  #pragma unroll
  for (int nt = 0; nt < 8; ++nt) {
    #pragma unroll
    for (int reg = 0; reg < 4; ++reg) {
      const size_t m = m0 + wave * 16 + quad * 4 + reg;
      const int n = nt * 16 + l16;
      Khi[m * 128 + n] = bf16hi(acc[nt][reg] + bias[nt]);
    }
  }
}

// -------------------------------------------------------------------------
// Decoder (R7): one block per batch row, 512 threads, 8 steps in-kernel.
// -------------------------------------------------------------------------
__global__ __launch_bounds__(512) void decoder(
    const unsigned short* __restrict__ Hhi, const unsigned short* __restrict__ Hlo,
    const unsigned short* __restrict__ Khi,
    const float* __restrict__ aWq, const float* __restrict__ abq,
    const float* __restrict__ av,
    const float* __restrict__ dwih, const float* __restrict__ dwhh,
    const float* __restrict__ dbih, const float* __restrict__ dbhh,
    const float* __restrict__ lng, const float* __restrict__ lnb,
    const float* __restrict__ w1, const float* __restrict__ b1,
    const float* __restrict__ w2, const float* __restrict__ b2,
    float* __restrict__ out)
{
  __shared__ float h_s[128], q_s[128], av_s[128], s_s[512], w_s[512];
  __shared__ float part[8][128], u_s[256], gx_s[384], gh_s[384], y_s[128];
  __shared__ float red[16];
  const int b = blockIdx.x, tid = threadIdx.x;
  const int wave = tid >> 6, lane = tid & 63;
  const int tslot = lane >> 4, ks = lane & 15;

  if (tid < 128) {
    const size_t base = ((size_t)(T_LEN - 1) * B_SZ + b) * 128 + tid;
    h_s[tid] = bf2f(Hhi[base]) + bf2f(Hlo[base]);
    av_s[tid] = av[tid];
  }
  __syncthreads();

  for (int step = 0; step < NSTEP; ++step) {
    if (tid < 128) {
      float acc = abq[tid];
      const float* wr = &aWq[(size_t)tid * 128];
      #pragma unroll 8
      for (int k4 = 0; k4 < 32; ++k4) {
        const float4 hv = *(const float4*)&h_s[k4 * 4];
        const float4 wv = *(const float4*)&wr[k4 * 4];
        acc += hv.x * wv.x + hv.y * wv.y + hv.z * wv.z + hv.w * wv.w;
      }
      q_s[tid] = acc;
    }
    __syncthreads();
    #pragma unroll 2
    for (int it = 0; it < 16; ++it) {
      const int t = it * 32 + wave * 4 + tslot;
      const size_t kb = ((size_t)t * B_SZ + b) * 128 + ks * 8;
      const uint4 uh = *(const uint4*)&Khi[kb];
      const float4 q0 = *(const float4*)&q_s[ks * 8];
      const float4 q1 = *(const float4*)&q_s[ks * 8 + 4];
      const float4 a0 = *(const float4*)&av_s[ks * 8];
      const float4 a1 = *(const float4*)&av_s[ks * 8 + 4];
      float acc = ftanh(bflo(uh.x) + q0.x) * a0.x + ftanh(bfhi(uh.x) + q0.y) * a0.y
                + ftanh(bflo(uh.y) + q0.z) * a0.z + ftanh(bfhi(uh.y) + q0.w) * a0.w
                + ftanh(bflo(uh.z) + q1.x) * a1.x + ftanh(bfhi(uh.z) + q1.y) * a1.y
                + ftanh(bflo(uh.w) + q1.z) * a1.z + ftanh(bfhi(uh.w) + q1.w) * a1.w;
      acc = row_sum16(acc);
      if (ks == 0) s_s[t] = acc;
    }
    __syncthreads();
    {
      const float sv = s_s[tid];
      float mx = sv;
      #pragma unroll
      for (int o = 32; o; o >>= 1) mx = fmaxf(mx, __shfl_xor(mx, o, 64));
      if (lane == 0) red[wave] = mx;
      __syncthreads();
      mx = red[0];
      #pragma unroll
      for (int i = 1; i < 8; ++i) mx = fmaxf(mx, red[i]);
      const float e = __expf(sv - mx);
      float sm = e;
      #pragma unroll
      for (int o = 32; o; o >>= 1) sm += __shfl_xor(sm, o, 64);
      if (lane == 0) red[8 + wave] = sm;
      __syncthreads();
      float tot = red[8];
      #pragma unroll
      for (int i = 1; i < 8; ++i) tot += red[8 + i];
      w_s[tid] = e / tot;
    }
    __syncthreads();
    {
      const int th = tid >> 6;
      const int c2 = (tid & 63) * 2;
      float acc0 = 0.0f, acc1 = 0.0f;
      #pragma unroll 4
      for (int q = 0; q < 64; ++q) {
        const int t = th * 64 + q;
        const unsigned u = *(const unsigned*)&Hhi[((size_t)t * B_SZ + b) * 128 + c2];
        const float wt = w_s[t];
        acc0 += wt * bflo(u);
        acc1 += wt * bfhi(u);
      }
      part[th][c2] = acc0;
      part[th][c2 + 1] = acc1;
    }
    __syncthreads();
    if (tid < 128) {
      float s = part[0][tid];
      #pragma unroll
      for (int i = 1; i < 8; ++i) s += part[i][tid];
      u_s[tid] = s;
      u_s[128 + tid] = h_s[tid];
    }
    __syncthreads();
    if (tid < 384) {
      const int j = tid;
      float gxv = dbih[j], ghv = dbhh[j];
      const float* wxr = &dwih[(size_t)j * 256];
      const float* whr = &dwhh[(size_t)j * 128];
      #pragma unroll 8
      for (int k4 = 0; k4 < 64; ++k4) {
        const float4 uv = *(const float4*)&u_s[k4 * 4];
        const float4 wv = *(const float4*)&wxr[k4 * 4];
        gxv += uv.x * wv.x + uv.y * wv.y + uv.z * wv.z + uv.w * wv.w;
      }
      #pragma unroll 8
      for (int k4 = 0; k4 < 32; ++k4) {
        const float4 hv = *(const float4*)&h_s[k4 * 4];
        const float4 wv = *(const float4*)&whr[k4 * 4];
        ghv += hv.x * wv.x + hv.y * wv.y + hv.z * wv.z + hv.w * wv.w;
      }
      gx_s[j] = gxv; gh_s[j] = ghv;
    }
    __syncthreads();
    if (tid < 128) {
      const float r = fsig(gx_s[tid] + gh_s[tid]);
      const float z = fsig(gx_s[128 + tid] + gh_s[128 + tid]);
      const float n = ftanh(gx_s[256 + tid] + r * gh_s[256 + tid]);
      const float hn = (1.0f - z) * n + z * h_s[tid];
      h_s[tid] = hn;
      float s1 = hn, s2 = hn * hn;
      #pragma unroll
      for (int o = 32; o; o >>= 1) { s1 += __shfl_xor(s1, o, 64); s2 += __shfl_xor(s2, o, 64); }
      if ((tid & 63) == 0) { red[tid >> 6] = s1; red[4 + (tid >> 6)] = s2; }
    }
    __syncthreads();
    if (tid < 128) {
      const float hn  = h_s[tid];
      const float mu  = (red[0] + red[1]) * (1.0f / 128.0f);
      const float var = (red[4] + red[5]) * (1.0f / 128.0f) - mu * mu;
      y_s[tid] = (hn - mu) / sqrtf(var + 1e-5f) * lng[tid] + lnb[tid];
    }
    __syncthreads();
    if (tid < 64) {
      float acc = b1[tid];
      const float* wr = &w1[(size_t)tid * 128];
      #pragma unroll 8
      for (int k4 = 0; k4 < 32; ++k4) {
        const float4 yv = *(const float4*)&y_s[k4 * 4];
        const float4 wv = *(const float4*)&wr[k4 * 4];
        acc += yv.x * wv.x + yv.y * wv.y + yv.z * wv.z + yv.w * wv.w;
      }
      acc = fmaxf(acc, 0.0f);
      float v = acc * w2[tid];
      #pragma unroll
      for (int o = 32; o; o >>= 1) v += __shfl_xor(v, o, 64);
      if (tid == 0) out[(size_t)b * NSTEP + step] = v + b2[0];
    }
    __syncthreads();
  }
}

// -------------------------------------------------------------------------
extern "C" void kernel_launch(void* const* d_in, const int* in_sizes, int n_in,
                              void* d_out, int out_size, void* d_ws, size_t ws_size,
                              hipStream_t stream)
{
  (void)in_sizes; (void)n_in; (void)out_size; (void)ws_size;
  const float* x    = (const float*)d_in[0];
  const float* ewih[3] = {(const float*)d_in[1], (const float*)d_in[5], (const float*)d_in[9]};
  const float* ewhh[3] = {(const float*)d_in[2], (const float*)d_in[6], (const float*)d_in[10]};
  const float* ebih[3] = {(const float*)d_in[3], (const float*)d_in[7], (const float*)d_in[11]};
  const float* ebhh[3] = {(const float*)d_in[4], (const float*)d_in[8], (const float*)d_in[12]};
  const float* aWq  = (const float*)d_in[13];
  const float* abq  = (const float*)d_in[14];
  const float* aWk  = (const float*)d_in[15];
  const float* abk  = (const float*)d_in[16];
  const float* av   = (const float*)d_in[17];
  const float* dwih = (const float*)d_in[18];
  const float* dwhh = (const float*)d_in[19];
  const float* dbih = (const float*)d_in[20];
  const float* dbhh = (const float*)d_in[21];
  const float* lng  = (const float*)d_in[22];
  const float* lnb  = (const float*)d_in[23];
  const float* w1   = (const float*)d_in[24];
  const float* b1   = (const float*)d_in[25];
  const float* w2   = (const float*)d_in[26];
  const float* b2   = (const float*)d_in[27];

  const size_t HN = (size_t)T_LEN * B_SZ * H_DIM;               // 33,554,432 elems
  unsigned short* Hhi = (unsigned short*)d_ws;                  // 64 MiB (T,B,H)
  unsigned short* Hlo = Hhi + HN;                               // 64 MiB
  float* regionC = (float*)(Hlo + HN);                          // 128 MiB
  unsigned short* Whi = (unsigned short*)(regionC + 25165824 + 65536);
  unsigned short* Wlo = Whi + 122880;
  unsigned short* Khi = (unsigned short*)regionC;               // decode: 64 MiB

  prep_split<<<dim3(480), dim3(256), 0, stream>>>(ewih[0], ewih[1], ewih[2], Whi, Wlo);

  rec_fused<1><<<dim3(256), dim3(512), 0, stream>>>(
      x, nullptr, nullptr, Whi, Wlo,
      ewhh[0], ebih[0], ebhh[0], Hhi, Hlo);
  rec_fused<0><<<dim3(256), dim3(512), 0, stream>>>(
      nullptr, Hhi, Hlo, Whi + 24576, Wlo + 24576,
      ewhh[1], ebih[1], ebhh[1], Hhi, Hlo);
  rec_fused<0><<<dim3(256), dim3(512), 0, stream>>>(
      nullptr, Hhi, Hlo, Whi + 73728, Wlo + 73728,
      ewhh[2], ebih[2], ebhh[2], Hhi, Hlo);

  keys_gemm<<<dim3(4096), dim3(256), 0, stream>>>(Hhi, Hlo, aWk, abk, Khi);
  decoder<<<dim3(512), dim3(512), 0, stream>>>(
      Hhi, Hlo, Khi, aWq, abq, av, dwih, dwhh, dbih, dbhh,
      lng, lnb, w1, b1, w2, b2, (float*)d_out);
}

// Round 3
// 2690.719 us; speedup vs baseline: 1.2490x; 1.2490x over previous
//
#include <hip/hip_runtime.h>
#include <hip/hip_bf16.h>
#include <cstdint>
#include <cstddef>

#define T_LEN 512
#define B_SZ  512
#define F_IN  64
#define H_DIM 128
#define NSTEP 8

typedef __attribute__((ext_vector_type(8))) short short8;
typedef __attribute__((ext_vector_type(4))) float f32x4;

__device__ __forceinline__ float fsig(float x) { return 1.0f / (1.0f + __expf(-x)); }
__device__ __forceinline__ float ftanh(float x) {
  float e = __expf(-2.0f * fabsf(x));
  float t = (1.0f - e) / (1.0f + e);
  return copysignf(t, x);
}
__device__ __forceinline__ unsigned short bf16hi(float x) {
  __hip_bfloat16 h = __float2bfloat16(x);
  return *(unsigned short*)&h;
}
__device__ __forceinline__ float bf2f(unsigned short u) {
  return __uint_as_float(((unsigned)u) << 16);
}
__device__ __forceinline__ float bflo(unsigned u) { return __uint_as_float(u << 16); }
__device__ __forceinline__ float bfhi(unsigned u) { return __uint_as_float(u & 0xffff0000u); }

// DPP cross-lane add within 16-lane rows (decoder scores)
template <int CTRL>
__device__ __forceinline__ float dpp_add(float v) {
  int p = __builtin_amdgcn_update_dpp(0, __float_as_int(v), CTRL, 0xF, 0xF, true);
  return v + __int_as_float(p);
}
__device__ __forceinline__ float row_sum16(float v) {
  v = dpp_add<0xB1>(v);
  v = dpp_add<0x4E>(v);
  v = dpp_add<0x124>(v);
  v = dpp_add<0x128>(v);
  return v;
}

// split 8 consecutive fp32 into bf16 hi/lo short8 fragments
__device__ __forceinline__ void split8(const float* p, short8& hi, short8& lo) {
  #pragma unroll
  for (int i = 0; i < 8; ++i) {
    const float v = p[i];
    const unsigned short h = bf16hi(v);
    hi[i] = (short)h;
    lo[i] = (short)bf16hi(v - bf2f(h));
  }
}

// split two adjacent float4 (8 fp32) into bf16 hi/lo short8 fragments
__device__ __forceinline__ void split_f4pair(const float4 a, const float4 b,
                                             short8& hi, short8& lo) {
  const float v[8] = {a.x, a.y, a.z, a.w, b.x, b.y, b.z, b.w};
  #pragma unroll
  for (int j = 0; j < 8; ++j) {
    const unsigned short h = bf16hi(v[j]);
    hi[j] = (short)h;
    lo[j] = (short)bf16hi(v[j] - bf2f(h));
  }
}

// -------------------------------------------------------------------------
// Split the 3 encoder w_ih matrices into bf16 hi/lo pairs (one-time prep).
// -------------------------------------------------------------------------
__global__ __launch_bounds__(256) void prep_split(
    const float* __restrict__ w0, const float* __restrict__ w1,
    const float* __restrict__ w2,
    unsigned short* __restrict__ hi, unsigned short* __restrict__ lo)
{
  const int i = blockIdx.x * 256 + threadIdx.x;
  if (i >= 122880) return;
  float v = (i < 24576) ? w0[i] : ((i < 73728) ? w1[i - 24576] : w2[i - 73728]);
  const unsigned short h = bf16hi(v);
  hi[i] = h;
  lo[i] = bf16hi(v - bf2f(h));
}

// -------------------------------------------------------------------------
// Fused GRU layer v3: ZERO global traffic inside the step loop.
//  - w_ih hi in LDS (XOR-swizzled, staged once), w_ih lo in 48 VGPRs
//  - w_hh hi/lo in 96 persistent VGPRs (proven structure)
//  - gx computed per 8-step group (full 16-row MFMA A-tile), results
//    parked in gxlds; steps read 6 floats via ds_read (no bpermute)
//  - h history buffered in hbuf LDS, flushed per group with coalesced
//    uint4 stores (no per-step global stores / RMW partial lines)
//  - X staged global->reg->LDS one group ahead (issue early, write late)
// Per step: barrier -> LDS reads -> 36 MFMA -> gates -> LDS writes.
// -------------------------------------------------------------------------
template <int IS_L0>
__global__ __launch_bounds__(512, 2) void rec_fused(
    const float* x,                         // layer0 input (B,T,F), else unused
    const unsigned short* Xhi,              // layers>=1: prev-layer H hi (T,B,H)
    const unsigned short* Xlo,
    const unsigned short* __restrict__ Wih_hi,  // (384, KD) bf16 hi
    const unsigned short* __restrict__ Wih_lo,  // (384, KD) bf16 lo
    const float* __restrict__ w_hh, const float* __restrict__ b_ih,
    const float* __restrict__ b_hh,
    unsigned short* Hhi, unsigned short* Hlo)   // out (T,B,H)
{
  constexpr int KD   = IS_L0 ? 64 : 128;
  constexpr int NCK  = KD / 32;
  constexpr int WROW = KD * 2;              // bytes per W row in LDS
  constexpr int WGRAN = WROW / 16;          // 16B granules per W row
  constexpr int XBUF = IS_L0 ? 4096 : 8192; // bytes per X stage buffer

  __shared__ unsigned short Wlds[384 * KD];          // w_ih hi, swizzled
  __shared__ float gxlds[8 * 2 * 384];               // group gx results
  __shared__ unsigned short hbh[2][2048], hbl[2][2048]; // h history (8t x 2r x 128)
  __shared__ unsigned short hsh[2][256], hsl[2][256];   // h double buffer
  __shared__ __align__(16) unsigned char Xraw[2][XBUF]; // staged X

  const int tid  = threadIdx.x;
  const int wv   = tid >> 6, lane = tid & 63;
  const int quad = lane >> 4, l16 = lane & 15;
  const int b0   = blockIdx.x * 2;
  const int c    = wv * 16 + l16;          // owned channel (quad-0 lanes)

  // ---- stage w_ih hi into LDS (swizzled: granule ^= row&7) ----
  {
    unsigned char* wb = (unsigned char*)Wlds;
    #pragma unroll
    for (int k = 0; k < (384 * WGRAN) / 512; ++k) {
      const int idx = k * 512 + tid;
      const int row = idx / WGRAN;
      const int gg  = idx % WGRAN;
      const uint4 v = *(const uint4*)&Wih_hi[(size_t)row * KD + gg * 8];
      *(uint4*)&wb[row * WROW + ((gg ^ (row & 7)) * 16)] = v;
    }
  }

  // ---- w_ih lo persistent fragments ----
  short8 Wl_[3][NCK];
  #pragma unroll
  for (int g_ = 0; g_ < 3; ++g_)
    #pragma unroll
    for (int ck = 0; ck < NCK; ++ck)
      Wl_[g_][ck] = *(const short8*)&Wih_lo[(size_t)(g_ * 128 + c) * KD + ck * 32 + quad * 8];

  // ---- w_hh persistent fragments (split from fp32) ----
  short8 Bh[3][4], Bl[3][4];
  #pragma unroll
  for (int g_ = 0; g_ < 3; ++g_)
    #pragma unroll
    for (int ck = 0; ck < 4; ++ck)
      split8(&w_hh[(size_t)(g_ * 128 + c) * 128 + ck * 32 + quad * 8],
             Bh[g_][ck], Bl[g_][ck]);

  float bias_r = 0.f, bias_z = 0.f, bihn = 0.f, bhhn = 0.f, h0 = 0.f, h1 = 0.f;
  if (quad == 0) {
    bias_r = b_ih[c] + b_hh[c];
    bias_z = b_ih[c + 128] + b_hh[c + 128];
    bihn = b_ih[c + 256];
    bhhn = b_hh[c + 256];
    hsh[0][c] = 0; hsh[0][128 + c] = 0;
    hsl[0][c] = 0; hsl[0][128 + c] = 0;
  }

  // ---- X staging machinery (thread-mapped, 1 uint4 per thread) ----
  const int t8 = tid & 255;
  const int sr = t8 >> 4;                  // staged row 0..15 (= 8t x 2b)
  const int sg = tid & 15;                 // 16B granule within row
  uint4 xr = {0, 0, 0, 0};

  auto load_xr = [&](int tgn) {
    if constexpr (IS_L0) {
      if (tid < 256)
        xr = *(const uint4*)&x[((size_t)(b0 + (sr & 1)) * T_LEN + tgn + (sr >> 1)) * 64 + sg * 4];
    } else {
      const unsigned short* src = (tid < 256) ? Xhi : Xlo;
      xr = *(const uint4*)&src[((size_t)(tgn + (sr >> 1)) * B_SZ + b0 + (sr & 1)) * 128 + sg * 8];
    }
  };
  auto store_xr = [&](int buf) {
    unsigned char* dstb = &Xraw[buf][0];
    const int off = sr * 256 + ((sg ^ (sr & 7)) * 16);
    if constexpr (IS_L0) {
      if (tid < 256) *(uint4*)&dstb[off] = xr;
    } else {
      *(uint4*)&dstb[(tid < 256 ? 0 : 4096) + off] = xr;
    }
  };
  auto flush_h = [&](int buf, int tp) {
    const int ft = t8 >> 5, fr = (t8 >> 4) & 1, fs = t8 & 15;
    const size_t go = ((size_t)(tp + ft) * B_SZ + b0 + fr) * 128 + fs * 8;
    const int lo_ = (ft * 2 + fr) * 128 + fs * 8;
    if (tid < 256) *(uint4*)&Hhi[go] = *(const uint4*)&hbh[buf][lo_];
    else           *(uint4*)&Hlo[go] = *(const uint4*)&hbl[buf][lo_];
  };

  // prologue: stage group 0, issue loads for group 1
  load_xr(0);
  store_xr(0);            // compiler inserts the vmcnt wait for xr
  load_xr(8);
  __syncthreads();

  for (int g = 0; g < 64; ++g) {
    // ---- flush previous group's h history (coalesced) ----
    if (g > 0) flush_h((g - 1) & 1, g * 8 - 8);

    // ---- gx for this group: A = 8 timesteps x 2 batch rows ----
    short8 Xhf[NCK], Xlf[NCK];
    {
      const unsigned char* xbuf = &Xraw[g & 1][0];
      if constexpr (IS_L0) {
        #pragma unroll
        for (int ck = 0; ck < 2; ++ck) {
          const int g0 = ck * 8 + quad * 2;
          const float4 f0 = *(const float4*)&xbuf[l16 * 256 + ((g0 ^ (l16 & 7)) * 16)];
          const float4 f1 = *(const float4*)&xbuf[l16 * 256 + (((g0 + 1) ^ (l16 & 7)) * 16)];
          split_f4pair(f0, f1, Xhf[ck], Xlf[ck]);
        }
      } else {
        #pragma unroll
        for (int ck = 0; ck < 4; ++ck) {
          const int go = ((ck * 4 + quad) ^ (l16 & 7)) * 16;
          Xhf[ck] = *(const short8*)&xbuf[l16 * 256 + go];
          Xlf[ck] = *(const short8*)&xbuf[4096 + l16 * 256 + go];
        }
      }
    }
    {
      f32x4 ax[3][2];
      #pragma unroll
      for (int g_ = 0; g_ < 3; ++g_) {
        ax[g_][0] = (f32x4){0.f, 0.f, 0.f, 0.f};
        ax[g_][1] = (f32x4){0.f, 0.f, 0.f, 0.f};
      }
      const unsigned char* wb = (const unsigned char*)Wlds;
      #pragma unroll
      for (int ck = 0; ck < NCK; ++ck) {
        const int p = (NCK == 4) ? (ck >> 1) : ck;
        #pragma unroll
        for (int g_ = 0; g_ < 3; ++g_) {
          const int n = g_ * 128 + c;
          const short8 wh = *(const short8*)&wb[n * WROW + (((ck * 4 + quad) ^ (n & 7)) * 16)];
          ax[g_][p] = __builtin_amdgcn_mfma_f32_16x16x32_bf16(Xhf[ck], wh, ax[g_][p], 0, 0, 0);
          ax[g_][p] = __builtin_amdgcn_mfma_f32_16x16x32_bf16(Xhf[ck], Wl_[g_][ck], ax[g_][p], 0, 0, 0);
          ax[g_][p] = __builtin_amdgcn_mfma_f32_16x16x32_bf16(Xlf[ck], wh, ax[g_][p], 0, 0, 0);
        }
      }
      // park gx in LDS: D row rr=quad*4+reg -> (tt = quad*2+(reg>>1), r = reg&1)
      #pragma unroll
      for (int g_ = 0; g_ < 3; ++g_)
        #pragma unroll
        for (int reg = 0; reg < 4; ++reg) {
          const int tt_ = quad * 2 + (reg >> 1);
          const int r_  = reg & 1;
          gxlds[(tt_ * 2 + r_) * 384 + g_ * 128 + c] = ax[g_][0][reg] + ax[g_][1][reg];
        }
    }
    __syncthreads();   // gxlds + staged X visible; hbuf flushed reads done

    // ---- 8 recurrence steps: pure LDS + MFMA + VALU ----
    #pragma unroll
    for (int tt = 0; tt < 8; ++tt) {
      // gate inputs from gxlds (issued early, hidden under MFMAs)
      float gr0 = 0.f, gz0 = 0.f, gn0 = 0.f, gr1 = 0.f, gz1 = 0.f, gn1 = 0.f;
      if (quad == 0) {
        const float* gp = &gxlds[tt * 768 + c];
        gr0 = gp[0];   gz0 = gp[128]; gn0 = gp[256];
        gr1 = gp[384]; gz1 = gp[512]; gn1 = gp[640];
      }

      // h A-fragments: lane row = l16; rows >=2 are zeros (C rows unused)
      short8 Ahf[4], Alf[4];
      if (l16 < 2) {
        #pragma unroll
        for (int ck = 0; ck < 4; ++ck) {
          const int ad = l16 * 128 + ck * 32 + quad * 8;
          Ahf[ck] = *(const short8*)&hsh[tt & 1][ad];
          Alf[ck] = *(const short8*)&hsl[tt & 1][ad];
        }
      } else {
        #pragma unroll
        for (int ck = 0; ck < 4; ++ck) {
          Ahf[ck] = (short8){0, 0, 0, 0, 0, 0, 0, 0};
          Alf[ck] = (short8){0, 0, 0, 0, 0, 0, 0, 0};
        }
      }

      f32x4 acc[3][2];
      #pragma unroll
      for (int g_ = 0; g_ < 3; ++g_) {
        acc[g_][0] = (f32x4){0.f, 0.f, 0.f, 0.f};
        acc[g_][1] = (f32x4){0.f, 0.f, 0.f, 0.f};
      }
      #pragma unroll
      for (int ck = 0; ck < 4; ++ck) {
        const int p = ck >> 1;
        #pragma unroll
        for (int g_ = 0; g_ < 3; ++g_) {
          acc[g_][p] = __builtin_amdgcn_mfma_f32_16x16x32_bf16(Ahf[ck], Bh[g_][ck], acc[g_][p], 0, 0, 0);
          acc[g_][p] = __builtin_amdgcn_mfma_f32_16x16x32_bf16(Ahf[ck], Bl[g_][ck], acc[g_][p], 0, 0, 0);
          acc[g_][p] = __builtin_amdgcn_mfma_f32_16x16x32_bf16(Alf[ck], Bh[g_][ck], acc[g_][p], 0, 0, 0);
        }
      }

      if (quad == 0) {
        const float ghr0 = acc[0][0][0] + acc[0][1][0];
        const float ghr1 = acc[0][0][1] + acc[0][1][1];
        const float ghz0 = acc[1][0][0] + acc[1][1][0];
        const float ghz1 = acc[1][0][1] + acc[1][1][1];
        const float ghn0 = acc[2][0][0] + acc[2][1][0];
        const float ghn1 = acc[2][0][1] + acc[2][1][1];
        const float r0 = fsig(gr0 + ghr0 + bias_r);
        const float z0 = fsig(gz0 + ghz0 + bias_z);
        const float nv0 = ftanh(gn0 + bihn + r0 * (ghn0 + bhhn));
        const float hn0 = (1.0f - z0) * nv0 + z0 * h0;
        const float r1 = fsig(gr1 + ghr1 + bias_r);
        const float z1 = fsig(gz1 + ghz1 + bias_z);
        const float nv1 = ftanh(gn1 + bihn + r1 * (ghn1 + bhhn));
        const float hn1 = (1.0f - z1) * nv1 + z1 * h1;
        h0 = hn0; h1 = hn1;
        const int nb = (tt + 1) & 1;
        const unsigned short hh0 = bf16hi(hn0), hh1 = bf16hi(hn1);
        const unsigned short hl0 = bf16hi(hn0 - bf2f(hh0));
        const unsigned short hl1 = bf16hi(hn1 - bf2f(hh1));
        hsh[nb][c] = hh0;       hsh[nb][128 + c] = hh1;
        hsl[nb][c] = hl0;       hsl[nb][128 + c] = hl1;
        const int hb = (tt * 2) * 128 + c;
        hbh[g & 1][hb] = hh0;       hbh[g & 1][hb + 128] = hh1;
        hbl[g & 1][hb] = hl0;       hbl[g & 1][hb + 128] = hl1;
      }

      // step 7: commit staged X for next group, then issue loads for g+2
      if (tt == 7 && g + 1 < 64) {
        store_xr((g + 1) & 1);       // vmcnt long since drained by barriers
        if (g + 2 < 64) load_xr((g + 2) * 8);
      }
      __syncthreads();
    }
  }
  // final flush (group 63)
  flush_h(1, 504);
}

// -------------------------------------------------------------------------
// keys = H @ aWk^T + abk, split-bf16 MFMA, output Khi (bf16 RNE) only.
// -------------------------------------------------------------------------
__global__ __launch_bounds__(256) void keys_gemm(
    const unsigned short* __restrict__ Ahi, const unsigned short* __restrict__ Alo,
    const float* __restrict__ aWk, const float* __restrict__ abk,
    unsigned short* __restrict__ Khi)
{
  __shared__ unsigned short Ah[64 * 40], Al[64 * 40];
  __shared__ unsigned short Bh[128 * 136], Bl[128 * 136];
  const int tid  = threadIdx.x;
  const int wave = tid >> 6, lane = tid & 63;
  const int quad = lane >> 4, l16 = lane & 15;
  const size_t m0 = (size_t)blockIdx.x * 64;

  for (int i = tid; i < 16384; i += 256) {
    const float v = aWk[i];
    const unsigned short h = bf16hi(v);
    const int r = i >> 7, k = i & 127;
    Bh[r * 136 + k] = h;
    Bl[r * 136 + k] = bf16hi(v - bf2f(h));
  }

  f32x4 acc[8];
  #pragma unroll
  for (int i = 0; i < 8; ++i) acc[i] = (f32x4){0.f, 0.f, 0.f, 0.f};
  float bias[8];
  #pragma unroll
  for (int nt = 0; nt < 8; ++nt) bias[nt] = abk[nt * 16 + l16];

  const int r = tid >> 2, c8 = (tid & 3) * 8;
  for (int kc = 0; kc < 128; kc += 32) {
    __syncthreads();
    const size_t src = (m0 + r) * 128 + kc + c8;
    *(uint4*)&Ah[r * 40 + c8] = *(const uint4*)&Ahi[src];
    *(uint4*)&Al[r * 40 + c8] = *(const uint4*)&Alo[src];
    __syncthreads();
    const short8 a_hi = *(const short8*)&Ah[(wave * 16 + l16) * 40 + quad * 8];
    const short8 a_lo = *(const short8*)&Al[(wave * 16 + l16) * 40 + quad * 8];
    #pragma unroll
    for (int nt = 0; nt < 8; ++nt) {
      const short8 b_hi = *(const short8*)&Bh[(nt * 16 + l16) * 136 + kc + quad * 8];
      const short8 b_lo = *(const short8*)&Bl[(nt * 16 + l16) * 136 + kc + quad * 8];
      acc[nt] = __builtin_amdgcn_mfma_f32_16x16x32_bf16(a_hi, b_hi, acc[nt], 0, 0, 0);
      acc[nt] = __builtin_amdgcn_mfma_f32_16x16x32_bf16(a_hi, b_lo, acc[nt], 0, 0, 0);
      acc[nt] = __builtin_amdgcn_mfma_f32_16x16x32_bf16(a_lo, b_hi, acc[nt], 0, 0, 0);
    }
  }
  #pragma unroll
  for (int nt = 0; nt < 8; ++nt) {
    #pragma unroll
    for (int reg = 0; reg < 4; ++reg) {
      const size_t m = m0 + wave * 16 + quad * 4 + reg;
      const int n = nt * 16 + l16;
      Khi[m * 128 + n] = bf16hi(acc[nt][reg] + bias[nt]);
    }
  }
}

// -------------------------------------------------------------------------
// Decoder (R7): one block per batch row, 512 threads, 8 steps in-kernel.
// -------------------------------------------------------------------------
__global__ __launch_bounds__(512) void decoder(
    const unsigned short* __restrict__ Hhi, const unsigned short* __restrict__ Hlo,
    const unsigned short* __restrict__ Khi,
    const float* __restrict__ aWq, const float* __restrict__ abq,
    const float* __restrict__ av,
    const float* __restrict__ dwih, const float* __restrict__ dwhh,
    const float* __restrict__ dbih, const float* __restrict__ dbhh,
    const float* __restrict__ lng, const float* __restrict__ lnb,
    const float* __restrict__ w1, const float* __restrict__ b1,
    const float* __restrict__ w2, const float* __restrict__ b2,
    float* __restrict__ out)
{
  __shared__ float h_s[128], q_s[128], av_s[128], s_s[512], w_s[512];
  __shared__ float part[8][128], u_s[256], gx_s[384], gh_s[384], y_s[128];
  __shared__ float red[16];
  const int b = blockIdx.x, tid = threadIdx.x;
  const int wave = tid >> 6, lane = tid & 63;
  const int tslot = lane >> 4, ks = lane & 15;

  if (tid < 128) {
    const size_t base = ((size_t)(T_LEN - 1) * B_SZ + b) * 128 + tid;
    h_s[tid] = bf2f(Hhi[base]) + bf2f(Hlo[base]);
    av_s[tid] = av[tid];
  }
  __syncthreads();

  for (int step = 0; step < NSTEP; ++step) {
    if (tid < 128) {
      float acc = abq[tid];
      const float* wr = &aWq[(size_t)tid * 128];
      #pragma unroll 8
      for (int k4 = 0; k4 < 32; ++k4) {
        const float4 hv = *(const float4*)&h_s[k4 * 4];
        const float4 wv = *(const float4*)&wr[k4 * 4];
        acc += hv.x * wv.x + hv.y * wv.y + hv.z * wv.z + hv.w * wv.w;
      }
      q_s[tid] = acc;
    }
    __syncthreads();
    #pragma unroll 2
    for (int it = 0; it < 16; ++it) {
      const int t = it * 32 + wave * 4 + tslot;
      const size_t kb = ((size_t)t * B_SZ + b) * 128 + ks * 8;
      const uint4 uh = *(const uint4*)&Khi[kb];
      const float4 q0 = *(const float4*)&q_s[ks * 8];
      const float4 q1 = *(const float4*)&q_s[ks * 8 + 4];
      const float4 a0 = *(const float4*)&av_s[ks * 8];
      const float4 a1 = *(const float4*)&av_s[ks * 8 + 4];
      float acc = ftanh(bflo(uh.x) + q0.x) * a0.x + ftanh(bfhi(uh.x) + q0.y) * a0.y
                + ftanh(bflo(uh.y) + q0.z) * a0.z + ftanh(bfhi(uh.y) + q0.w) * a0.w
                + ftanh(bflo(uh.z) + q1.x) * a1.x + ftanh(bfhi(uh.z) + q1.y) * a1.y
                + ftanh(bflo(uh.w) + q1.z) * a1.z + ftanh(bfhi(uh.w) + q1.w) * a1.w;
      acc = row_sum16(acc);
      if (ks == 0) s_s[t] = acc;
    }
    __syncthreads();
    {
      const float sv = s_s[tid];
      float mx = sv;
      #pragma unroll
      for (int o = 32; o; o >>= 1) mx = fmaxf(mx, __shfl_xor(mx, o, 64));
      if (lane == 0) red[wave] = mx;
      __syncthreads();
      mx = red[0];
      #pragma unroll
      for (int i = 1; i < 8; ++i) mx = fmaxf(mx, red[i]);
      const float e = __expf(sv - mx);
      float sm = e;
      #pragma unroll
      for (int o = 32; o; o >>= 1) sm += __shfl_xor(sm, o, 64);
      if (lane == 0) red[8 + wave] = sm;
      __syncthreads();
      float tot = red[8];
      #pragma unroll
      for (int i = 1; i < 8; ++i) tot += red[8 + i];
      w_s[tid] = e / tot;
    }
    __syncthreads();
    {
      const int th = tid >> 6;
      const int c2 = (tid & 63) * 2;
      float acc0 = 0.0f, acc1 = 0.0f;
      #pragma unroll 4
      for (int q = 0; q < 64; ++q) {
        const int t = th * 64 + q;
        const unsigned u = *(const unsigned*)&Hhi[((size_t)t * B_SZ + b) * 128 + c2];
        const float wt = w_s[t];
        acc0 += wt * bflo(u);
        acc1 += wt * bfhi(u);
      }
      part[th][c2] = acc0;
      part[th][c2 + 1] = acc1;
    }
    __syncthreads();
    if (tid < 128) {
      float s = part[0][tid];
      #pragma unroll
      for (int i = 1; i < 8; ++i) s += part[i][tid];
      u_s[tid] = s;
      u_s[128 + tid] = h_s[tid];
    }
    __syncthreads();
    if (tid < 384) {
      const int j = tid;
      float gxv = dbih[j], ghv = dbhh[j];
      const float* wxr = &dwih[(size_t)j * 256];
      const float* whr = &dwhh[(size_t)j * 128];
      #pragma unroll 8
      for (int k4 = 0; k4 < 64; ++k4) {
        const float4 uv = *(const float4*)&u_s[k4 * 4];
        const float4 wv = *(const float4*)&wxr[k4 * 4];
        gxv += uv.x * wv.x + uv.y * wv.y + uv.z * wv.z + uv.w * wv.w;
      }
      #pragma unroll 8
      for (int k4 = 0; k4 < 32; ++k4) {
        const float4 hv = *(const float4*)&h_s[k4 * 4];
        const float4 wv = *(const float4*)&whr[k4 * 4];
        ghv += hv.x * wv.x + hv.y * wv.y + hv.z * wv.z + hv.w * wv.w;
      }
      gx_s[j] = gxv; gh_s[j] = ghv;
    }
    __syncthreads();
    if (tid < 128) {
      const float r = fsig(gx_s[tid] + gh_s[tid]);
      const float z = fsig(gx_s[128 + tid] + gh_s[128 + tid]);
      const float n = ftanh(gx_s[256 + tid] + r * gh_s[256 + tid]);
      const float hn = (1.0f - z) * n + z * h_s[tid];
      h_s[tid] = hn;
      float s1 = hn, s2 = hn * hn;
      #pragma unroll
      for (int o = 32; o; o >>= 1) { s1 += __shfl_xor(s1, o, 64); s2 += __shfl_xor(s2, o, 64); }
      if ((tid & 63) == 0) { red[tid >> 6] = s1; red[4 + (tid >> 6)] = s2; }
    }
    __syncthreads();
    if (tid < 128) {
      const float hn  = h_s[tid];
      const float mu  = (red[0] + red[1]) * (1.0f / 128.0f);
      const float var = (red[4] + red[5]) * (1.0f / 128.0f) - mu * mu;
      y_s[tid] = (hn - mu) / sqrtf(var + 1e-5f) * lng[tid] + lnb[tid];
    }
    __syncthreads();
    if (tid < 64) {
      float acc = b1[tid];
      const float* wr = &w1[(size_t)tid * 128];
      #pragma unroll 8
      for (int k4 = 0; k4 < 32; ++k4) {
        const float4 yv = *(const float4*)&y_s[k4 * 4];
        const float4 wv = *(const float4*)&wr[k4 * 4];
        acc += yv.x * wv.x + yv.y * wv.y + yv.z * wv.z + yv.w * wv.w;
      }
      acc = fmaxf(acc, 0.0f);
      float v = acc * w2[tid];
      #pragma unroll
      for (int o = 32; o; o >>= 1) v += __shfl_xor(v, o, 64);
      if (tid == 0) out[(size_t)b * NSTEP + step] = v + b2[0];
    }
    __syncthreads();
  }
}

// -------------------------------------------------------------------------
extern "C" void kernel_launch(void* const* d_in, const int* in_sizes, int n_in,
                              void* d_out, int out_size, void* d_ws, size_t ws_size,
                              hipStream_t stream)
{
  (void)in_sizes; (void)n_in; (void)out_size; (void)ws_size;
  const float* x    = (const float*)d_in[0];
  const float* ewih[3] = {(const float*)d_in[1], (const float*)d_in[5], (const float*)d_in[9]};
  const float* ewhh[3] = {(const float*)d_in[2], (const float*)d_in[6], (const float*)d_in[10]};
  const float* ebih[3] = {(const float*)d_in[3], (const float*)d_in[7], (const float*)d_in[11]};
  const float* ebhh[3] = {(const float*)d_in[4], (const float*)d_in[8], (const float*)d_in[12]};
  const float* aWq  = (const float*)d_in[13];
  const float* abq  = (const float*)d_in[14];
  const float* aWk  = (const float*)d_in[15];
  const float* abk  = (const float*)d_in[16];
  const float* av   = (const float*)d_in[17];
  const float* dwih = (const float*)d_in[18];
  const float* dwhh = (const float*)d_in[19];
  const float* dbih = (const float*)d_in[20];
  const float* dbhh = (const float*)d_in[21];
  const float* lng  = (const float*)d_in[22];
  const float* lnb  = (const float*)d_in[23];
  const float* w1   = (const float*)d_in[24];
  const float* b1   = (const float*)d_in[25];
  const float* w2   = (const float*)d_in[26];
  const float* b2   = (const float*)d_in[27];

  const size_t HN = (size_t)T_LEN * B_SZ * H_DIM;               // 33,554,432 elems
  unsigned short* Hhi = (unsigned short*)d_ws;                  // 64 MiB (T,B,H)
  unsigned short* Hlo = Hhi + HN;                               // 64 MiB
  float* regionC = (float*)(Hlo + HN);                          // 128 MiB
  unsigned short* Whi = (unsigned short*)(regionC + 25165824 + 65536);
  unsigned short* Wlo = Whi + 122880;
  unsigned short* Khi = (unsigned short*)regionC;               // decode: 64 MiB

  prep_split<<<dim3(480), dim3(256), 0, stream>>>(ewih[0], ewih[1], ewih[2], Whi, Wlo);

  rec_fused<1><<<dim3(256), dim3(512), 0, stream>>>(
      x, nullptr, nullptr, Whi, Wlo,
      ewhh[0], ebih[0], ebhh[0], Hhi, Hlo);
  rec_fused<0><<<dim3(256), dim3(512), 0, stream>>>(
      nullptr, Hhi, Hlo, Whi + 24576, Wlo + 24576,
      ewhh[1], ebih[1], ebhh[1], Hhi, Hlo);
  rec_fused<0><<<dim3(256), dim3(512), 0, stream>>>(
      nullptr, Hhi, Hlo, Whi + 73728, Wlo + 73728,
      ewhh[2], ebih[2], ebhh[2], Hhi, Hlo);

  keys_gemm<<<dim3(4096), dim3(256), 0, stream>>>(Hhi, Hlo, aWk, abk, Khi);
  decoder<<<dim3(512), dim3(512), 0, stream>>>(
      Hhi, Hlo, Khi, aWq, abq, av, dwih, dwhh, dbih, dbhh,
      lng, lnb, w1, b1, w2, b2, (float*)d_out);
}